// Round 2
// baseline (1943.134 us; speedup 1.0000x reference)
//
#include <hip/hip_runtime.h>

#define N_IN 128
#define HID 256
#define NB 16
#define BM 128
#define HS2 136         // bf16 row stride for HALF-K H tile (272 B rows: 16B-aligned, 2-way banks = free)
#define BS_STRIDE 17    // basis LDS stride (f32)

typedef __attribute__((ext_vector_type(8))) short s8v;   // 8 bf16 = 4 VGPRs
typedef __attribute__((ext_vector_type(4))) float f4v;   // MFMA 16x16x32 accumulator

__device__ __forceinline__ unsigned short f2bf(float f) {
  unsigned int u = __float_as_uint(f);
  u += 0x7fffu + ((u >> 16) & 1u);   // round-to-nearest-even
  return (unsigned short)(u >> 16);
}

__device__ __forceinline__ float tanh_fast(float x) {
  float e = __expf(2.0f * x);
  return 1.0f - 2.0f * __builtin_amdgcn_rcpf(e + 1.0f);
}

// Fragment-ordered bf16 repack (1 KB coalesced MFMA fragments), as round 2.
// W1f frag (pass,kk,ct): n = pass*128+ct*16+l15, k = kk*32+quad*8+j, val = W1[k*256+n]
// W2f frag (b,kk,ct):    n = ct*16+l15,          k = kk*32+quad*8+j, val = W2[k*2048+n*16+b]
__global__ void prep_kernel(const float* __restrict__ W1, const float* __restrict__ W2,
                            unsigned short* __restrict__ W1f, unsigned short* __restrict__ W2f) {
  int tid = blockIdx.x * blockDim.x + threadIdx.x;
  if (tid < N_IN * HID) {
    int j = tid & 7, lane = (tid >> 3) & 63, ct = (tid >> 9) & 7, kk = (tid >> 12) & 3, pass = tid >> 14;
    int n = pass * 128 + ct * 16 + (lane & 15);
    int k = kk * 32 + (lane >> 4) * 8 + j;
    W1f[tid] = f2bf(W1[k * HID + n]);
  }
  int i = tid - N_IN * HID;
  if (i >= 0 && i < HID * (N_IN * NB)) {
    int j = i & 7, lane = (i >> 3) & 63, ct = (i >> 9) & 7, kk = (i >> 12) & 7, b = i >> 15;
    int n = ct * 16 + (lane & 15);
    int k = kk * 32 + (lane >> 4) * 8 + j;
    W2f[i] = f2bf(W2[k * (N_IN * NB) + n * 16 + b]);
  }
}

// K-half interleaved: B(h0) -> bar -> C(h0) -> bar -> B(h1) -> bar -> C(h1).
// Hs holds only one 128-col K-half => LDS 43.5 KB => 3 blocks/CU (3 waves/SIMD),
// up from 2. Occupancy was the binding constraint (MfmaUtil model: 40% == 2-wave
// MFMA issue floor exactly).
__global__ void __launch_bounds__(256, 3)
pilayer_kernel(const float* __restrict__ prop,
               const int* __restrict__ idx_i,
               const int* __restrict__ idx_j,
               const float* __restrict__ basis,
               const unsigned short* __restrict__ W1f,
               const unsigned short* __restrict__ W2f,
               float* __restrict__ out, int P) {
  __shared__ unsigned short Hs[BM * HS2];         // 34,816 B (one K-half of H)
  __shared__ float basisS[BM * BS_STRIDE];        //  8,704 B  -> 43,520 B total

  const int t = threadIdx.x;
  const int lane = t & 63;
  const int wv = t >> 6;
  const int l15 = lane & 15;
  const int l4 = lane >> 4;
  const int tile0 = blockIdx.x * BM;
  const int row0 = wv * 32;

  // ---- edge indices at kernel top: head of the idx->prop pointer-chase ----
  int pidx[2], qidx[2];
#pragma unroll
  for (int rt = 0; rt < 2; ++rt) {
    int p = tile0 + row0 + rt * 16 + l15; if (p >= P) p = P - 1;
    pidx[rt] = idx_i[p];
    qidx[rt] = idx_j[p];
  }

  // ---- stage basis tile cooperatively (nt loads: basis streamed exactly once) ----
  {
    int r = t >> 1;
    int c0 = (t & 1) * 8;
    int p = tile0 + r; if (p >= P) p = P - 1;
    const f4v* bp = (const f4v*)(basis + (long)p * NB + c0);
    f4v b0 = __builtin_nontemporal_load(bp);
    f4v b1 = __builtin_nontemporal_load(bp + 1);
    float* dst = &basisS[r * BS_STRIDE + c0];
    dst[0] = b0[0]; dst[1] = b0[1]; dst[2] = b0[2]; dst[3] = b0[3];
    dst[4] = b1[0]; dst[5] = b1[1]; dst[6] = b1[2]; dst[7] = b1[3];
  }

  // ---- gathers hoisted: issued ONCE, A-fragments live through both halves ----
  s8v afr[4][2];   // [kk][rt], 32 VGPR
#pragma unroll
  for (int kk = 0; kk < 4; ++kk) {
    int k0 = kk * 32 + l4 * 8;
#pragma unroll
    for (int rt = 0; rt < 2; ++rt) {
      const float4* ai = (const float4*)(prop + (long)pidx[rt] * N_IN + k0);
      const float4* aj = (const float4*)(prop + (long)qidx[rt] * N_IN + k0);
      float4 x0 = ai[0], x1 = ai[1];
      float4 y0 = aj[0], y1 = aj[1];
      s8v a;
      a[0] = (short)f2bf(x0.x + y0.x); a[1] = (short)f2bf(x0.y + y0.y);
      a[2] = (short)f2bf(x0.z + y0.z); a[3] = (short)f2bf(x0.w + y0.w);
      a[4] = (short)f2bf(x1.x + y1.x); a[5] = (short)f2bf(x1.y + y1.y);
      a[6] = (short)f2bf(x1.z + y1.z); a[7] = (short)f2bf(x1.w + y1.w);
      afr[kk][rt] = a;
    }
  }

  // ---- output accumulators persist across both K-halves (AGPR-resident) ----
  const int rg = wv >> 1, cg = wv & 1;
  const int rbase = rg * 64;
  f4v o[4][4];   // [rt][q] -> rows rbase+rt*16.., cols (cg*4+q)*16..
#pragma unroll
  for (int rt = 0; rt < 4; ++rt)
#pragma unroll
    for (int q = 0; q < 4; ++q) o[rt][q] = (f4v){0.f, 0.f, 0.f, 0.f};

#pragma unroll 1
  for (int half = 0; half < 2; ++half) {
    if (half) __syncthreads();   // all waves done reading Hs(half 0) before overwrite

    // ---- Phase B(half): wave wv computes H rows [32*wv,32*wv+32), cols half*128..+128 ----
    {
      f4v acc[2][8];
#pragma unroll
      for (int rt = 0; rt < 2; ++rt)
#pragma unroll
        for (int ct = 0; ct < 8; ++ct) acc[rt][ct] = (f4v){0.f, 0.f, 0.f, 0.f};
#pragma unroll
      for (int kk = 0; kk < 4; ++kk) {
#pragma unroll
        for (int ct = 0; ct < 8; ++ct) {
          s8v bfr = *(const s8v*)(W1f + ((((half * 4 + kk) * 8 + ct) * 64 + lane) << 3));
#pragma unroll
          for (int rt = 0; rt < 2; ++rt)
            acc[rt][ct] = __builtin_amdgcn_mfma_f32_16x16x32_bf16(afr[kk][rt], bfr, acc[rt][ct], 0, 0, 0);
        }
      }
#pragma unroll
      for (int rt = 0; rt < 2; ++rt)
#pragma unroll
        for (int ct = 0; ct < 8; ++ct)
#pragma unroll
          for (int r = 0; r < 4; ++r) {
            int lrow = row0 + rt * 16 + l4 * 4 + r;
            int col = ct * 16 + l15;                    // LOCAL column within this half
            Hs[lrow * HS2 + col] = f2bf(tanh_fast(acc[rt][ct][r]));
          }
    }

    __syncthreads();   // H(half) + basis visible to all waves

    // ---- Phase C(half): wave (rg,cg) owns rows rg*64..+64, cols cg*64..+64;
    //      K restricted to this half's 128 hidden units ----
    {
      // A-cache: 16 fragments, reused across all 16 b and 4 q (AGPR-eligible)
      s8v areg[4][4];   // [rt][kloc]
#pragma unroll
      for (int rt = 0; rt < 4; ++rt)
#pragma unroll
        for (int kloc = 0; kloc < 4; ++kloc)
          areg[rt][kloc] = *(const s8v*)&Hs[(rbase + rt * 16 + l15) * HS2 +
                                            kloc * 32 + l4 * 8];

      s8v bf[4][4];   // register ring of B fragments [slot][kloc], slot = it & 3
      // preload iterations 0,1,2  (b=0, q=0..2)
#pragma unroll
      for (int q0 = 0; q0 < 3; ++q0)
#pragma unroll
        for (int kloc = 0; kloc < 4; ++kloc)
          bf[q0][kloc] = *(const s8v*)(W2f +
              ((((half * 4 + kloc) * 8) + cg * 4 + q0) << 9) + lane * 8);

#pragma unroll 1
      for (int b = 0; b < 16; ++b) {
        float bs[4][4];
#pragma unroll
        for (int rt = 0; rt < 4; ++rt)
#pragma unroll
          for (int r = 0; r < 4; ++r)
            bs[rt][r] = basisS[(rbase + rt * 16 + l4 * 4 + r) * BS_STRIDE + b];

#pragma unroll
        for (int q = 0; q < 4; ++q) {
          // prefetch iteration it+3 into slot (q+3)&3  (it = b*4+q)
          {
            int nb = b + ((q + 3) >> 2); if (nb > 15) nb = 15;   // tail: harmless re-read
            int nq = (q + 3) & 3;
#pragma unroll
            for (int kloc = 0; kloc < 4; ++kloc)
              bf[(q + 3) & 3][kloc] = *(const s8v*)(W2f +
                  (((nb * 8 + half * 4 + kloc) * 8 + cg * 4 + nq) << 9) + lane * 8);
          }
          f4v g[4];
#pragma unroll
          for (int rt = 0; rt < 4; ++rt) g[rt] = (f4v){0.f, 0.f, 0.f, 0.f};
          __builtin_amdgcn_s_setprio(1);   // T5: barrier-free independent waves in b-loop
#pragma unroll
          for (int kloc = 0; kloc < 4; ++kloc)
#pragma unroll
            for (int rt = 0; rt < 4; ++rt)
              g[rt] = __builtin_amdgcn_mfma_f32_16x16x32_bf16(areg[rt][kloc], bf[q][kloc], g[rt], 0, 0, 0);
          __builtin_amdgcn_s_setprio(0);
#pragma unroll
          for (int rt = 0; rt < 4; ++rt)
#pragma unroll
            for (int r = 0; r < 4; ++r)
              o[rt][q][r] += g[rt][r] * bs[rt][r];
        }
      }
    }
  }

  // ---- epilogue: out[p][c], c = (cg*4+q)*16 + l15. Non-temporal: out is
  // write-once/never-read -> keep it from evicting W2f out of L2. ----
#pragma unroll
  for (int rt = 0; rt < 4; ++rt)
#pragma unroll
    for (int r = 0; r < 4; ++r) {
      int p = tile0 + rbase + rt * 16 + l4 * 4 + r;
      if (p < P) {
        float* op = out + (long)p * N_IN + cg * 64 + l15;
#pragma unroll
        for (int q = 0; q < 4; ++q)
          __builtin_nontemporal_store(o[rt][q][r], op + q * 16);
      }
    }
}

extern "C" void kernel_launch(void* const* d_in, const int* in_sizes, int n_in,
                              void* d_out, int out_size, void* d_ws, size_t ws_size,
                              hipStream_t stream) {
  const float* prop  = (const float*)d_in[0];
  const int* idx_i   = (const int*)d_in[1];
  const int* idx_j   = (const int*)d_in[2];
  const float* basis = (const float*)d_in[3];
  const float* W1    = (const float*)d_in[4];
  const float* W2    = (const float*)d_in[5];
  float* out = (float*)d_out;
  int P = in_sizes[1];

  unsigned short* W1f = (unsigned short*)d_ws;                 // 32768 bf16
  unsigned short* W2f = W1f + N_IN * HID;                      // 524288 bf16

  int prep_threads = N_IN * HID + HID * N_IN * NB;             // 557056
  prep_kernel<<<(prep_threads + 255) / 256, 256, 0, stream>>>(W1, W2, W1f, W2f);

  int ntiles = (P + BM - 1) / BM;
  pilayer_kernel<<<ntiles, 256, 0, stream>>>(prop, idx_i, idx_j, basis, W1f, W2f, out, P);
}

// Round 3
// 424.122 us; speedup vs baseline: 4.5815x; 4.5815x over previous
//
#include <hip/hip_runtime.h>

#define N_IN 128
#define HID 256
#define NB 16
#define BM 128
#define HS_STRIDE 264   // bf16 row stride for H tile (16B pad -> 2-way banks only, free)
#define BS_STRIDE 17    // basis LDS stride (f32)

typedef __attribute__((ext_vector_type(8))) short s8v;   // 8 bf16 = 4 VGPRs
typedef __attribute__((ext_vector_type(4))) float f4v;   // MFMA 16x16x32 accumulator

__device__ __forceinline__ unsigned short f2bf(float f) {
  unsigned int u = __float_as_uint(f);
  u += 0x7fffu + ((u >> 16) & 1u);   // round-to-nearest-even
  return (unsigned short)(u >> 16);
}

__device__ __forceinline__ float tanh_fast(float x) {
  float e = __expf(2.0f * x);
  return 1.0f - 2.0f * __builtin_amdgcn_rcpf(e + 1.0f);
}

// Fragment-ordered bf16 repack (1 KB coalesced MFMA fragments).
// W1f frag (pass,kk,ct): n = pass*128+ct*16+l15, k = kk*32+quad*8+j, val = W1[k*256+n]
// W2f frag (b,kk,ct):    n = ct*16+l15,          k = kk*32+quad*8+j, val = W2[k*2048+n*16+b]
__global__ void prep_kernel(const float* __restrict__ W1, const float* __restrict__ W2,
                            unsigned short* __restrict__ W1f, unsigned short* __restrict__ W2f) {
  int tid = blockIdx.x * blockDim.x + threadIdx.x;
  if (tid < N_IN * HID) {
    int j = tid & 7, lane = (tid >> 3) & 63, ct = (tid >> 9) & 7, kk = (tid >> 12) & 3, pass = tid >> 14;
    int n = pass * 128 + ct * 16 + (lane & 15);
    int k = kk * 32 + (lane >> 4) * 8 + j;
    W1f[tid] = f2bf(W1[k * HID + n]);
  }
  int i = tid - N_IN * HID;
  if (i >= 0 && i < HID * (N_IN * NB)) {
    int j = i & 7, lane = (i >> 3) & 63, ct = (i >> 9) & 7, kk = (i >> 12) & 7, b = i >> 15;
    int n = ct * 16 + (lane & 15);
    int k = kk * 32 + (lane >> 4) * 8 + j;
    W2f[i] = f2bf(W2[k * (N_IN * NB) + n * 16 + b]);
  }
}

// Round-3: occupancy via 512-thread blocks (8 waves) with HALVED per-wave tiles.
// Phase order identical to round-1 (B -> one barrier -> C): phase B and C register
// live-ranges stay DISJOINT (round-2 lesson: interleaving merged them -> 7.6 GB spill).
// LDS 76.3 KB -> 2 blocks/CU = 16 waves/CU = 4 waves/SIMD, provided regs/wave <= 128:
// phase C peak = o[2][4](32,AGPR) + areg[2][4](32) + bf[2][4](32) + g/bs(16) + addr(~16).
__global__ void __launch_bounds__(512, 4)
pilayer_kernel(const float* __restrict__ prop,
               const int* __restrict__ idx_i,
               const int* __restrict__ idx_j,
               const float* __restrict__ basis,
               const unsigned short* __restrict__ W1f,
               const unsigned short* __restrict__ W2f,
               float* __restrict__ out, int P) {
  __shared__ unsigned short Hs[BM * HS_STRIDE];   // 67,584 B
  __shared__ float basisS[BM * BS_STRIDE];        //  8,704 B  -> 76.3 KB total

  const int t = threadIdx.x;
  const int lane = t & 63;
  const int wv = t >> 6;           // 0..7
  const int l15 = lane & 15;
  const int l4 = lane >> 4;
  const int tile0 = blockIdx.x * BM;
  const int row0 = wv * 16;        // phase-B: 16 H-rows per wave

  // ---- edge indices at kernel top: head of the idx->prop pointer-chase ----
  int pidx, qidx;
  {
    int p = tile0 + row0 + l15; if (p >= P) p = P - 1;
    pidx = idx_i[p];
    qidx = idx_j[p];
  }

  // ---- stage basis tile cooperatively (nt loads: basis streamed exactly once) ----
  {
    int r = t >> 2;                // 0..127
    int c0 = (t & 3) * 4;          // one float4 per thread
    int p = tile0 + r; if (p >= P) p = P - 1;
    const f4v* bp = (const f4v*)(basis + (long)p * NB + c0);
    f4v b0 = __builtin_nontemporal_load(bp);
    float* dst = &basisS[r * BS_STRIDE + c0];
    dst[0] = b0[0]; dst[1] = b0[1]; dst[2] = b0[2]; dst[3] = b0[3];
  }

  // ---- Phase B: wave wv computes H rows [16*wv, 16*wv+16), all 256 cols ----
  {
    s8v afr[4];   // [kk], 16 VGPR; gathers issued ONCE, reused by both passes
#pragma unroll
    for (int kk = 0; kk < 4; ++kk) {
      int k0 = kk * 32 + l4 * 8;
      const float4* ai = (const float4*)(prop + (long)pidx * N_IN + k0);
      const float4* aj = (const float4*)(prop + (long)qidx * N_IN + k0);
      float4 x0 = ai[0], x1 = ai[1];
      float4 y0 = aj[0], y1 = aj[1];
      s8v a;
      a[0] = (short)f2bf(x0.x + y0.x); a[1] = (short)f2bf(x0.y + y0.y);
      a[2] = (short)f2bf(x0.z + y0.z); a[3] = (short)f2bf(x0.w + y0.w);
      a[4] = (short)f2bf(x1.x + y1.x); a[5] = (short)f2bf(x1.y + y1.y);
      a[6] = (short)f2bf(x1.z + y1.z); a[7] = (short)f2bf(x1.w + y1.w);
      afr[kk] = a;
    }
#pragma unroll
    for (int pass = 0; pass < 2; ++pass) {
      f4v acc[8];
#pragma unroll
      for (int ct = 0; ct < 8; ++ct) acc[ct] = (f4v){0.f, 0.f, 0.f, 0.f};
#pragma unroll
      for (int kk = 0; kk < 4; ++kk) {
#pragma unroll
        for (int ct = 0; ct < 8; ++ct) {
          s8v bfr = *(const s8v*)(W1f + ((((pass * 4 + kk) * 8 + ct) * 64 + lane) << 3));
          acc[ct] = __builtin_amdgcn_mfma_f32_16x16x32_bf16(afr[kk], bfr, acc[ct], 0, 0, 0);
        }
      }
#pragma unroll
      for (int ct = 0; ct < 8; ++ct)
#pragma unroll
        for (int r = 0; r < 4; ++r) {
          int lrow = row0 + l4 * 4 + r;
          int col = pass * 128 + ct * 16 + l15;
          Hs[lrow * HS_STRIDE + col] = f2bf(tanh_fast(acc[ct][r]));
        }
    }
  }

  __syncthreads();   // H + basis visible to all waves

  // ---- Phase C: 4x2 wave partition; wave (rg,cg) owns rows rg*32..+32, cols cg*64..+64.
  // A (H) cached in registers per K-half; B double-buffered in registers from global W2f
  // (L2-resident: nt out-stores keep it from being evicted). ----
  const int rg = wv >> 1, cg = wv & 1;
  const int rbase = rg * 32;

  f4v o[2][4];   // [rt][q] -> rows rbase+rt*16.., cols (cg*4+q)*16..
#pragma unroll
  for (int rt = 0; rt < 2; ++rt)
#pragma unroll
    for (int q = 0; q < 4; ++q) o[rt][q] = (f4v){0.f, 0.f, 0.f, 0.f};

#pragma unroll 1
  for (int khalf = 0; khalf < 2; ++khalf) {
    // A-cache: 8 fragments (32 VGPR), reused across all 16 b and 4 q
    s8v areg[2][4];   // [rt][kloc]
#pragma unroll
    for (int rt = 0; rt < 2; ++rt)
#pragma unroll
      for (int kloc = 0; kloc < 4; ++kloc)
        areg[rt][kloc] = *(const s8v*)&Hs[(rbase + rt * 16 + l15) * HS_STRIDE +
                                          (khalf * 4 + kloc) * 32 + l4 * 8];

    s8v bf[2][4];   // register double-buffer of B fragments [parity][kloc]
    // preload (b=0, q=0)
#pragma unroll
    for (int kloc = 0; kloc < 4; ++kloc)
      bf[0][kloc] = *(const s8v*)(W2f + ((((khalf * 4 + kloc) * 8) + cg * 4) << 9) + lane * 8);

#pragma unroll 1
    for (int b = 0; b < 16; ++b) {
      float bs[2][4];
#pragma unroll
      for (int rt = 0; rt < 2; ++rt)
#pragma unroll
        for (int r = 0; r < 4; ++r)
          bs[rt][r] = basisS[(rbase + rt * 16 + l4 * 4 + r) * BS_STRIDE + b];

#pragma unroll
      for (int q = 0; q < 4; ++q) {
        const int cur = q & 1;           // parity of it = b*4+q (b*4 even) -> compile-time
        // prefetch next iteration's 4 B-fragments into the other buffer
        {
          int nb = (q == 3) ? (b + 1 < 16 ? b + 1 : 15) : b;
          int nq = (q + 1) & 3;
#pragma unroll
          for (int kloc = 0; kloc < 4; ++kloc)
            bf[cur ^ 1][kloc] = *(const s8v*)(W2f +
                (((nb * 8 + khalf * 4 + kloc) * 8 + cg * 4 + nq) << 9) + lane * 8);
        }
        f4v g[2];
#pragma unroll
        for (int rt = 0; rt < 2; ++rt) g[rt] = (f4v){0.f, 0.f, 0.f, 0.f};
        __builtin_amdgcn_s_setprio(1);   // T5: barrier-free independent waves in b-loop
#pragma unroll
        for (int kloc = 0; kloc < 4; ++kloc)
#pragma unroll
          for (int rt = 0; rt < 2; ++rt)
            g[rt] = __builtin_amdgcn_mfma_f32_16x16x32_bf16(areg[rt][kloc], bf[cur][kloc], g[rt], 0, 0, 0);
        __builtin_amdgcn_s_setprio(0);
#pragma unroll
        for (int rt = 0; rt < 2; ++rt)
#pragma unroll
          for (int r = 0; r < 4; ++r)
            o[rt][q][r] += g[rt][r] * bs[rt][r];
      }
    }
  }

  // ---- epilogue: out[p][c], c = (cg*4+q)*16 + l15. Non-temporal: out is
  // write-once/never-read -> keep it from evicting W2f out of L2. ----
#pragma unroll
  for (int rt = 0; rt < 2; ++rt)
#pragma unroll
    for (int r = 0; r < 4; ++r) {
      int p = tile0 + rbase + rt * 16 + l4 * 4 + r;
      if (p < P) {
        float* op = out + (long)p * N_IN + cg * 64 + l15;
#pragma unroll
        for (int q = 0; q < 4; ++q)
          __builtin_nontemporal_store(o[rt][q][r], op + q * 16);
      }
    }
}

extern "C" void kernel_launch(void* const* d_in, const int* in_sizes, int n_in,
                              void* d_out, int out_size, void* d_ws, size_t ws_size,
                              hipStream_t stream) {
  const float* prop  = (const float*)d_in[0];
  const int* idx_i   = (const int*)d_in[1];
  const int* idx_j   = (const int*)d_in[2];
  const float* basis = (const float*)d_in[3];
  const float* W1    = (const float*)d_in[4];
  const float* W2    = (const float*)d_in[5];
  float* out = (float*)d_out;
  int P = in_sizes[1];

  unsigned short* W1f = (unsigned short*)d_ws;                 // 32768 bf16
  unsigned short* W2f = W1f + N_IN * HID;                      // 524288 bf16

  int prep_threads = N_IN * HID + HID * N_IN * NB;             // 557056
  prep_kernel<<<(prep_threads + 255) / 256, 256, 0, stream>>>(W1, W2, W1f, W2f);

  int ntiles = (P + BM - 1) / BM;
  pilayer_kernel<<<ntiles, 512, 0, stream>>>(prop, idx_i, idx_j, basis, W1f, W2f, out, P);
}

// Round 4
// 368.806 us; speedup vs baseline: 5.2687x; 1.1500x over previous
//
#include <hip/hip_runtime.h>

#define N_IN 128
#define HID 256
#define NB 16
#define BM 128
#define HS_STRIDE 264   // bf16 row stride for H tile (16B pad -> 2-way banks only, free)
#define BS_STRIDE 17    // basis LDS stride (f32)

typedef __attribute__((ext_vector_type(8))) short s8v;   // 8 bf16 = 4 VGPRs
typedef __attribute__((ext_vector_type(4))) float f4v;   // MFMA 16x16x32 accumulator
typedef __attribute__((ext_vector_type(2))) float f2v;   // packed-f32 pair (v_pk_fma_f32)

__device__ __forceinline__ unsigned short f2bf(float f) {
  unsigned int u = __float_as_uint(f);
  u += 0x7fffu + ((u >> 16) & 1u);   // round-to-nearest-even
  return (unsigned short)(u >> 16);
}

__device__ __forceinline__ float tanh_fast(float x) {
  float e = __expf(2.0f * x);
  return 1.0f - 2.0f * __builtin_amdgcn_rcpf(e + 1.0f);
}

// Fragment-ordered bf16 repack (1 KB coalesced MFMA fragments).
// W1f frag (pass,kk,ct): n = pass*128+ct*16+l15, k = kk*32+quad*8+j, val = W1[k*256+n]
// W2f frag (b,kk,ct):    n = ct*16+l15,          k = kk*32+quad*8+j, val = W2[k*2048+n*16+b]
__global__ void prep_kernel(const float* __restrict__ W1, const float* __restrict__ W2,
                            unsigned short* __restrict__ W1f, unsigned short* __restrict__ W2f) {
  int tid = blockIdx.x * blockDim.x + threadIdx.x;
  if (tid < N_IN * HID) {
    int j = tid & 7, lane = (tid >> 3) & 63, ct = (tid >> 9) & 7, kk = (tid >> 12) & 3, pass = tid >> 14;
    int n = pass * 128 + ct * 16 + (lane & 15);
    int k = kk * 32 + (lane >> 4) * 8 + j;
    W1f[tid] = f2bf(W1[k * HID + n]);
  }
  int i = tid - N_IN * HID;
  if (i >= 0 && i < HID * (N_IN * NB)) {
    int j = i & 7, lane = (i >> 3) & 63, ct = (i >> 9) & 7, kk = (i >> 12) & 7, b = i >> 15;
    int n = ct * 16 + (lane & 15);
    int k = kk * 32 + (lane >> 4) * 8 + j;
    W2f[i] = f2bf(W2[k * (N_IN * NB) + n * 16 + b]);
  }
}

// Round-4: round-1 structure (proven 253us; 64-row waves keep B-side L2 traffic at
// 2MB/block -- round-3 lesson: 32-row waves double it and hit the L2 BW wall).
// Deltas: (1) b-loop unroll 2 (cross-b scheduling), (2) packed v_pk_fma_f32 o-update,
// (3) khalf=0 ring preload hoisted above the barrier.
__global__ void __launch_bounds__(256, 2)
pilayer_kernel(const float* __restrict__ prop,
               const int* __restrict__ idx_i,
               const int* __restrict__ idx_j,
               const float* __restrict__ basis,
               const unsigned short* __restrict__ W1f,
               const unsigned short* __restrict__ W2f,
               float* __restrict__ out, int P) {
  __shared__ unsigned short Hs[BM * HS_STRIDE];   // 67,584 B (live through phase C)
  __shared__ float basisS[BM * BS_STRIDE];        //  8,704 B  -> 76.3 KB, 2 blocks/CU

  const int t = threadIdx.x;
  const int lane = t & 63;
  const int wv = t >> 6;
  const int l15 = lane & 15;
  const int l4 = lane >> 4;
  const int tile0 = blockIdx.x * BM;
  const int row0 = wv * 32;

  // ---- edge indices at kernel top: head of the idx->prop pointer-chase ----
  int pidx[2], qidx[2];
#pragma unroll
  for (int rt = 0; rt < 2; ++rt) {
    int p = tile0 + row0 + rt * 16 + l15; if (p >= P) p = P - 1;
    pidx[rt] = idx_i[p];
    qidx[rt] = idx_j[p];
  }

  // ---- stage basis tile cooperatively (nt loads: basis streamed exactly once) ----
  {
    int r = t >> 1;
    int c0 = (t & 1) * 8;
    int p = tile0 + r; if (p >= P) p = P - 1;
    const f4v* bp = (const f4v*)(basis + (long)p * NB + c0);
    f4v b0 = __builtin_nontemporal_load(bp);
    f4v b1 = __builtin_nontemporal_load(bp + 1);
    float* dst = &basisS[r * BS_STRIDE + c0];
    dst[0] = b0[0]; dst[1] = b0[1]; dst[2] = b0[2]; dst[3] = b0[3];
    dst[4] = b1[0]; dst[5] = b1[1]; dst[6] = b1[2]; dst[7] = b1[3];
  }

  // ---- Phase B: wave wv computes H rows [32*wv, 32*wv+32), all 256 cols ----
  // Gathers hoisted OUT of the pass loop: issued once, reused by both passes.
  {
    s8v afr[4][2];   // [kk][rt], 32 VGPR
#pragma unroll
    for (int kk = 0; kk < 4; ++kk) {
      int k0 = kk * 32 + l4 * 8;
#pragma unroll
      for (int rt = 0; rt < 2; ++rt) {
        const float4* ai = (const float4*)(prop + (long)pidx[rt] * N_IN + k0);
        const float4* aj = (const float4*)(prop + (long)qidx[rt] * N_IN + k0);
        float4 x0 = ai[0], x1 = ai[1];
        float4 y0 = aj[0], y1 = aj[1];
        s8v a;
        a[0] = (short)f2bf(x0.x + y0.x); a[1] = (short)f2bf(x0.y + y0.y);
        a[2] = (short)f2bf(x0.z + y0.z); a[3] = (short)f2bf(x0.w + y0.w);
        a[4] = (short)f2bf(x1.x + y1.x); a[5] = (short)f2bf(x1.y + y1.y);
        a[6] = (short)f2bf(x1.z + y1.z); a[7] = (short)f2bf(x1.w + y1.w);
        afr[kk][rt] = a;
      }
    }
#pragma unroll
    for (int pass = 0; pass < 2; ++pass) {
      f4v acc[2][8];
#pragma unroll
      for (int rt = 0; rt < 2; ++rt)
#pragma unroll
        for (int ct = 0; ct < 8; ++ct) acc[rt][ct] = (f4v){0.f, 0.f, 0.f, 0.f};
#pragma unroll
      for (int kk = 0; kk < 4; ++kk) {
#pragma unroll
        for (int ct = 0; ct < 8; ++ct) {
          s8v bfr = *(const s8v*)(W1f + ((((pass * 4 + kk) * 8 + ct) * 64 + lane) << 3));
#pragma unroll
          for (int rt = 0; rt < 2; ++rt)
            acc[rt][ct] = __builtin_amdgcn_mfma_f32_16x16x32_bf16(afr[kk][rt], bfr, acc[rt][ct], 0, 0, 0);
        }
      }
#pragma unroll
      for (int rt = 0; rt < 2; ++rt)
#pragma unroll
        for (int ct = 0; ct < 8; ++ct)
#pragma unroll
          for (int r = 0; r < 4; ++r) {
            int lrow = row0 + rt * 16 + l4 * 4 + r;
            int col = pass * 128 + ct * 16 + l15;
            Hs[lrow * HS_STRIDE + col] = f2bf(tanh_fast(acc[rt][ct][r]));
          }
    }
  }

  // ---- Phase C wave partition (needed for preload addressing) ----
  const int rg = wv >> 1, cg = wv & 1;
  const int rbase = rg * 64;

  // ---- khalf=0 ring preload HOISTED ABOVE the barrier: the 12 B-loads are
  // in flight while this wave waits for the slowest phase-B wave. ----
  s8v bf[4][4];   // register ring of B fragments [slot][kloc], slot = it & 3
#pragma unroll
  for (int q0 = 0; q0 < 3; ++q0)
#pragma unroll
    for (int kloc = 0; kloc < 4; ++kloc)
      bf[q0][kloc] = *(const s8v*)(W2f + (((kloc * 8) + cg * 4 + q0) << 9) + lane * 8);

  __syncthreads();   // H + basis visible to all waves

  // ---- Phase C: 2x2 wave partition; wave (rg,cg) owns rows rg*64..+64, cols cg*64..+64.
  // A (H) cached in registers per K-half; B prefetched from W2f at distance 3. ----
  f4v o[4][4];   // [rt][q] -> rows rbase+rt*16.., cols (cg*4+q)*16..
#pragma unroll
  for (int rt = 0; rt < 4; ++rt)
#pragma unroll
    for (int q = 0; q < 4; ++q) o[rt][q] = (f4v){0.f, 0.f, 0.f, 0.f};

#pragma unroll 1
  for (int khalf = 0; khalf < 2; ++khalf) {
    if (khalf) {   // khalf=1 ring preload (khalf=0's was done pre-barrier)
#pragma unroll
      for (int q0 = 0; q0 < 3; ++q0)
#pragma unroll
        for (int kloc = 0; kloc < 4; ++kloc)
          bf[q0][kloc] = *(const s8v*)(W2f +
              ((((4 + kloc) * 8) + cg * 4 + q0) << 9) + lane * 8);
    }

    // A-cache: 16 fragments (64 VGPR), reused across all 16 b and 4 q
    s8v areg[4][4];   // [rt][kloc]
#pragma unroll
    for (int rt = 0; rt < 4; ++rt)
#pragma unroll
      for (int kloc = 0; kloc < 4; ++kloc)
        areg[rt][kloc] = *(const s8v*)&Hs[(rbase + rt * 16 + l15) * HS_STRIDE +
                                          (khalf * 4 + kloc) * 32 + l4 * 8];

#pragma unroll 2
    for (int b = 0; b < 16; ++b) {
      float bs[4][4];
#pragma unroll
      for (int rt = 0; rt < 4; ++rt)
#pragma unroll
        for (int r = 0; r < 4; ++r)
          bs[rt][r] = basisS[(rbase + rt * 16 + l4 * 4 + r) * BS_STRIDE + b];

#pragma unroll
      for (int q = 0; q < 4; ++q) {
        const int cur = q & 1;           // parity of it = b*4+q is q&1 -> compile-time
        // prefetch iteration it+3 into slot (q+3)&3  (it = b*4+q)
        {
          int nb = b + ((q + 3) >> 2); if (nb > 15) nb = 15;   // tail: harmless re-read
          int nq = (q + 3) & 3;
#pragma unroll
          for (int kloc = 0; kloc < 4; ++kloc)
            bf[(q + 3) & 3][kloc] = *(const s8v*)(W2f +
                (((nb * 8 + khalf * 4 + kloc) * 8 + cg * 4 + nq) << 9) + lane * 8);
        }
        f4v g[4];
#pragma unroll
        for (int rt = 0; rt < 4; ++rt) g[rt] = (f4v){0.f, 0.f, 0.f, 0.f};
        __builtin_amdgcn_s_setprio(1);   // T5: barrier-free independent waves in b-loop
#pragma unroll
        for (int kloc = 0; kloc < 4; ++kloc)
#pragma unroll
          for (int rt = 0; rt < 4; ++rt)
            g[rt] = __builtin_amdgcn_mfma_f32_16x16x32_bf16(areg[rt][kloc], bf[q & 3][kloc], g[rt], 0, 0, 0);
        __builtin_amdgcn_s_setprio(0);
        (void)cur;
        // packed o-update: 2x v_pk_fma_f32 per rt instead of 4x v_fma_f32
#pragma unroll
        for (int rt = 0; rt < 4; ++rt) {
          f2v glo = {g[rt][0], g[rt][1]}, ghi = {g[rt][2], g[rt][3]};
          f2v blo = {bs[rt][0], bs[rt][1]}, bhi = {bs[rt][2], bs[rt][3]};
          f2v olo = {o[rt][q][0], o[rt][q][1]}, ohi = {o[rt][q][2], o[rt][q][3]};
          olo = __builtin_elementwise_fma(glo, blo, olo);
          ohi = __builtin_elementwise_fma(ghi, bhi, ohi);
          o[rt][q][0] = olo[0]; o[rt][q][1] = olo[1];
          o[rt][q][2] = ohi[0]; o[rt][q][3] = ohi[1];
        }
      }
    }
  }

  // ---- epilogue: out[p][c], c = (cg*4+q)*16 + l15. Non-temporal: out is
  // write-once/never-read -> keep it from evicting W2f out of L2. ----
#pragma unroll
  for (int rt = 0; rt < 4; ++rt)
#pragma unroll
    for (int r = 0; r < 4; ++r) {
      int p = tile0 + rbase + rt * 16 + l4 * 4 + r;
      if (p < P) {
        float* op = out + (long)p * N_IN + cg * 64 + l15;
#pragma unroll
        for (int q = 0; q < 4; ++q)
          __builtin_nontemporal_store(o[rt][q][r], op + q * 16);
      }
    }
}

extern "C" void kernel_launch(void* const* d_in, const int* in_sizes, int n_in,
                              void* d_out, int out_size, void* d_ws, size_t ws_size,
                              hipStream_t stream) {
  const float* prop  = (const float*)d_in[0];
  const int* idx_i   = (const int*)d_in[1];
  const int* idx_j   = (const int*)d_in[2];
  const float* basis = (const float*)d_in[3];
  const float* W1    = (const float*)d_in[4];
  const float* W2    = (const float*)d_in[5];
  float* out = (float*)d_out;
  int P = in_sizes[1];

  unsigned short* W1f = (unsigned short*)d_ws;                 // 32768 bf16
  unsigned short* W2f = W1f + N_IN * HID;                      // 524288 bf16

  int prep_threads = N_IN * HID + HID * N_IN * NB;             // 557056
  prep_kernel<<<(prep_threads + 255) / 256, 256, 0, stream>>>(W1, W2, W1f, W2f);

  int ntiles = (P + BM - 1) / BM;
  pilayer_kernel<<<ntiles, 256, 0, stream>>>(prop, idx_i, idx_j, basis, W1f, W2f, out, P);
}